// Round 9
// baseline (46.290 us; speedup 1.0000x reference)
//
#include <hip/hip_runtime.h>

#define NV 8
#define NB 16
#define LMAX 4096
#define ND 1024
#define EPS_ 1e-6f
// exp(-10*s) == exp2(s * (-10*log2(e)))
#define NEXP10 (-14.426950408889634f)

#define NSEG 32                           // weight segments per batch (128 rows each)
// ws layout: wbuf[NB][LMAX][NV] f32 (2 MB), then pden2[NB][NSEG][NV] (16 KB)
#define W_FLOATS ((size_t)NB * LMAX * NV)

// 512 blocks x 256 thr. Block: b = bid&15, seg = bid>>4. Thread t: row
// l = seg*128 + (t>>1), v-half h = t&1 -> computes 4 weights, one float4 store.
__global__ __launch_bounds__(256) void dvs_weights(
    const float* __restrict__ centers,
    const int* __restrict__ grid_thws,
    float* __restrict__ wbuf,             // [NB][LMAX][NV]
    float* __restrict__ pden2)            // [NB][NSEG][NV]
{
    const int bid = blockIdx.x;
    const int b   = bid & (NB - 1);
    const int seg = bid >> 4;
    const int H  = grid_thws[b * 3 + 1];
    const int W  = grid_thws[b * 3 + 2];
    const int HW = H * W;
    const int t  = threadIdx.x;
    const int l  = seg * 128 + (t >> 1);
    const int h  = t & 1;                 // v-half: 0 -> v0..3, 1 -> v4..7

    const float invH = 1.0f / (float)H;
    const float invW = 1.0f / (float)W;
    const int i = l / W;
    const int j = l - i * W;
    const float y = ((float)i + 0.5f) * invH;
    const float x = ((float)j + 0.5f) * invW;

    float p[4];
#pragma unroll
    for (int k = 0; k < 4; ++k) {
        const float2 c = ((const float2*)centers)[b * NV + h * 4 + k];
        const float dx = c.x - x;
        const float dy = c.y - y;
        const float s  = fmaf(dy, dy, dx * dx);
        p[k] = (l < HW) ? exp2f(s * NEXP10) : 0.0f;
    }
    ((float4*)wbuf)[(size_t)(b * LMAX + l) * 2 + h] =
        make_float4(p[0], p[1], p[2], p[3]);

    // den partials: butterfly over lanes of same parity (parity = v-half)
#pragma unroll
    for (int m = 2; m <= 32; m <<= 1) {
        p[0] += __shfl_xor(p[0], m);
        p[1] += __shfl_xor(p[1], m);
        p[2] += __shfl_xor(p[2], m);
        p[3] += __shfl_xor(p[3], m);
    }
    __shared__ float pd[4][NV];
    const int wv   = t >> 6;              // wave 0..3
    const int lane = t & 63;
    if (lane < 2)                         // lane0: v0..3 sums, lane1: v4..7 sums
        *(float4*)&pd[wv][lane * 4] = make_float4(p[0], p[1], p[2], p[3]);
    __syncthreads();
    if (t < NV)
        pden2[(b * NSEG + seg) * NV + t] = pd[0][t] + pd[1][t] + pd[2][t] + pd[3][t];
}

// 512 blocks x 256 thr. Block: b = bid>>5, slice = bid&31 (32 floats of d).
// Thread t: row-in-group rg = t>>3, float4-in-slice lane = t&7.
// Iterates ALL rows of batch b (rows split mod-32 across rg); per-thread
// register accumulation; rg-reduction via shuffles + LDS at the end.
__global__ __launch_bounds__(256, 2) void dvs_accum(
    const float* __restrict__ v_pad,
    const float* __restrict__ wbuf,
    const float* __restrict__ pden2,
    const int* __restrict__ grid_thws,
    float* __restrict__ out)
{
    const int bid   = blockIdx.x;
    const int b     = bid >> 5;
    const int slice = bid & 31;
    const int HW = grid_thws[b * 3 + 1] * grid_thws[b * 3 + 2];
    const int ng = (HW + 31) >> 5;        // 32-row groups; ng >= 32 since HW >= 1024
    const int t    = threadIdx.x;
    const int rg   = t >> 3;              // row within group, 0..31
    const int lane = t & 7;               // float4 within 32-float slice

    __shared__ float dls[NV];
    __shared__ float4 red[4][8][NV];      // wave, lane, view — 4 KB
    if (t < NV) {
        float s = 0.0f;
#pragma unroll
        for (int g = 0; g < NSEG; ++g) s += pden2[(b * NSEG + g) * NV + t];
        dls[t] = s;
    }

    const float4* __restrict__ src =
        (const float4*)v_pad + (size_t)b * LMAX * (ND / 4) + slice * 8 + lane;
    const float4* __restrict__ w4 =
        (const float4*)wbuf + (size_t)b * LMAX * 2;
    // row l: data src[l*256]; weights w4[l*2] (v0..3), w4[l*2+1] (v4..7)

    float4 acc[NV];
#pragma unroll
    for (int v = 0; v < NV; ++v) acc[v] = make_float4(0.f, 0.f, 0.f, 0.f);

    // 2-deep prefetch (ng >= 32 so both prologue groups exist)
    const int lA = rg;
    const int lB = 32 + rg;
    float4 dA = src[(size_t)lA * 256];
    float4 wA0 = w4[lA * 2], wA1 = w4[lA * 2 + 1];
    float4 dB = src[(size_t)lB * 256];
    float4 wB0 = w4[lB * 2], wB1 = w4[lB * 2 + 1];

    for (int g = 0; g < ng; ++g) {
        float4 dC = dB, wC0 = wB0, wC1 = wB1;
        const int lC = (g + 2) * 32 + rg;
        if (g + 2 < ng) {                 // uniform branch
            dC  = src[(size_t)lC * 256];
            wC0 = w4[lC * 2];
            wC1 = w4[lC * 2 + 1];
        }
        acc[0].x = fmaf(wA0.x, dA.x, acc[0].x);
        acc[0].y = fmaf(wA0.x, dA.y, acc[0].y);
        acc[0].z = fmaf(wA0.x, dA.z, acc[0].z);
        acc[0].w = fmaf(wA0.x, dA.w, acc[0].w);
        acc[1].x = fmaf(wA0.y, dA.x, acc[1].x);
        acc[1].y = fmaf(wA0.y, dA.y, acc[1].y);
        acc[1].z = fmaf(wA0.y, dA.z, acc[1].z);
        acc[1].w = fmaf(wA0.y, dA.w, acc[1].w);
        acc[2].x = fmaf(wA0.z, dA.x, acc[2].x);
        acc[2].y = fmaf(wA0.z, dA.y, acc[2].y);
        acc[2].z = fmaf(wA0.z, dA.z, acc[2].z);
        acc[2].w = fmaf(wA0.z, dA.w, acc[2].w);
        acc[3].x = fmaf(wA0.w, dA.x, acc[3].x);
        acc[3].y = fmaf(wA0.w, dA.y, acc[3].y);
        acc[3].z = fmaf(wA0.w, dA.z, acc[3].z);
        acc[3].w = fmaf(wA0.w, dA.w, acc[3].w);
        acc[4].x = fmaf(wA1.x, dA.x, acc[4].x);
        acc[4].y = fmaf(wA1.x, dA.y, acc[4].y);
        acc[4].z = fmaf(wA1.x, dA.z, acc[4].z);
        acc[4].w = fmaf(wA1.x, dA.w, acc[4].w);
        acc[5].x = fmaf(wA1.y, dA.x, acc[5].x);
        acc[5].y = fmaf(wA1.y, dA.y, acc[5].y);
        acc[5].z = fmaf(wA1.y, dA.z, acc[5].z);
        acc[5].w = fmaf(wA1.y, dA.w, acc[5].w);
        acc[6].x = fmaf(wA1.z, dA.x, acc[6].x);
        acc[6].y = fmaf(wA1.z, dA.y, acc[6].y);
        acc[6].z = fmaf(wA1.z, dA.z, acc[6].z);
        acc[6].w = fmaf(wA1.z, dA.w, acc[6].w);
        acc[7].x = fmaf(wA1.w, dA.x, acc[7].x);
        acc[7].y = fmaf(wA1.w, dA.y, acc[7].y);
        acc[7].z = fmaf(wA1.w, dA.z, acc[7].z);
        acc[7].w = fmaf(wA1.w, dA.w, acc[7].w);
        dA = dB; wA0 = wB0; wA1 = wB1;
        dB = dC; wB0 = wC0; wB1 = wC1;
    }

    // ---- rg-reduction (was missing in R8 — the bug) ----
    // in-wave: rg bits 3..5 of t -> butterfly masks 8,16,32
#pragma unroll
    for (int v = 0; v < NV; ++v) {
#pragma unroll
        for (int m = 8; m <= 32; m <<= 1) {
            acc[v].x += __shfl_xor(acc[v].x, m);
            acc[v].y += __shfl_xor(acc[v].y, m);
            acc[v].z += __shfl_xor(acc[v].z, m);
            acc[v].w += __shfl_xor(acc[v].w, m);
        }
    }
    // cross-wave: lanes 0..7 of each wave hold the wave's sum
    const int wv     = t >> 6;
    const int lane64 = t & 63;
    if (lane64 < 8) {
#pragma unroll
        for (int v = 0; v < NV; ++v) red[wv][lane64][v] = acc[v];
    }
    __syncthreads();
    if (t < 64) {
        const int ln = t & 7;             // float4 within slice
        const int v  = t >> 3;            // view
        float4 s0 = red[0][ln][v], s1 = red[1][ln][v];
        float4 s2 = red[2][ln][v], s3 = red[3][ln][v];
        const float inv = 1.0f / (dls[v] + EPS_);
        float4 o = make_float4((s0.x + s1.x + s2.x + s3.x) * inv,
                               (s0.y + s1.y + s2.y + s3.y) * inv,
                               (s0.z + s1.z + s2.z + s3.z) * inv,
                               (s0.w + s1.w + s2.w + s3.w) * inv);
        ((float4*)out)[(size_t)b * NV * (ND / 4) + v * (ND / 4) + slice * 8 + ln] = o;
    }
}

extern "C" void kernel_launch(void* const* d_in, const int* in_sizes, int n_in,
                              void* d_out, int out_size, void* d_ws, size_t ws_size,
                              hipStream_t stream) {
    const float* v_pad     = (const float*)d_in[0];
    const float* centers   = (const float*)d_in[1];
    // d_in[2] = v_len (== H*W), unused
    const int*   grid_thws = (const int*)d_in[3];

    float* wbuf  = (float*)d_ws;
    float* pden2 = wbuf + W_FLOATS;

    dvs_weights<<<NB * NSEG, 256, 0, stream>>>(centers, grid_thws, wbuf, pden2);
    dvs_accum<<<NB * 32, 256, 0, stream>>>(v_pad, wbuf, pden2, grid_thws, (float*)d_out);
}

// Round 10
// 33.169 us; speedup vs baseline: 1.3956x; 1.3956x over previous
//
#include <hip/hip_runtime.h>

#define NV 8
#define NB 16
#define LMAX 4096
#define ND 1024
#define CHUNK 128
#define NCHUNK (LMAX / CHUNK)   // 32 chunks -> 512 blocks
#define EPS_ 1e-6f
// exp(-10*s) == exp2(s * (-10*log2(e)))
#define NEXP10 (-14.426950408889634f)

// ws layout: pnum[NB][NCHUNK][NV][ND] floats (16 MB), then pden[NB][NCHUNK][NV]
#define PNUM_FLOATS ((size_t)NB * NCHUNK * NV * ND)

__global__ __launch_bounds__(256, 4) void dvs_accum(
    const float* __restrict__ v_pad,
    const float* __restrict__ centers,
    const int* __restrict__ grid_thws,
    float* __restrict__ pnum,
    float* __restrict__ pden)
{
    const int bid   = blockIdx.x;
    const int b     = bid >> 5;             // / NCHUNK
    const int chunk = bid & (NCHUNK - 1);
    const int H  = grid_thws[b * 3 + 1];
    const int W  = grid_thws[b * 3 + 2];
    const int HW = H * W;
    const int l0 = chunk * CHUNK;
    if (l0 >= HW) return;                   // fully-masked chunk: no reads, no writes
    // valid rows in this chunk, rounded up to pipeline granularity (4)
    const int rr = (min(CHUNK, HW - l0) + 3) & ~3;

    __shared__ __align__(16) float wlds[CHUNK][NV];   // 4 KB: weights w[row][view]

    const int t = threadIdx.x;

    // ---- issue the first 4 row-loads BEFORE the weight phase (independent)
    const float4* __restrict__ src =
        (const float4*)v_pad + ((size_t)b * LMAX + l0) * (ND / 4) + t;
    float4 c0 = src[0 * 256];
    float4 c1 = src[1 * 256];
    float4 c2 = src[2 * 256];
    float4 c3 = src[3 * 256];

    // ---- weight phase: 1024 weights, 4 per thread, once per block
    const float invH = 1.0f / (float)H;
    const float invW = 1.0f / (float)W;
#pragma unroll
    for (int g = 0; g < 4; ++g) {
        const int idx = t + g * 256;
        const int row = idx >> 3;           // 0..127
        const int v   = idx & 7;
        const int l   = l0 + row;
        const int i   = l / W;
        const int j   = l - i * W;
        const float y = ((float)i + 0.5f) * invH;
        const float x = ((float)j + 0.5f) * invW;
        const float2 c = ((const float2*)centers)[b * NV + v];
        const float dx = c.x - x;
        const float dy = c.y - y;
        const float s  = fmaf(dy, dy, dx * dx);
        wlds[row][v] = (l < HW) ? exp2f(s * NEXP10) : 0.0f;
    }
    __syncthreads();

    // ---- pden: wave 0, lane handles (rg = t>>3, v = t&7): 16 rows each,
    //      then butterfly over rg bits (masks 8,16,32)
    const size_t pbase = (size_t)(b * NCHUNK + chunk) * NV;
    if (t < 64) {
        const int rg = t >> 3;
        const int v  = t & 7;
        float s = 0.0f;
#pragma unroll
        for (int k = 0; k < CHUNK / 8; ++k) s += wlds[rg + 8 * k][v];
        s += __shfl_xor(s, 8);
        s += __shfl_xor(s, 16);
        s += __shfl_xor(s, 32);
        if (rg == 0) pden[pbase + v] = s;
    }

    float acc[NV][4];
#pragma unroll
    for (int v = 0; v < NV; ++v)
#pragma unroll
        for (int k = 0; k < 4; ++k) acc[v][k] = 0.0f;

    auto proc = [&](const int r, const float4 r4) {
        float w[NV];
        *(float4*)&w[0] = *(const float4*)&wlds[r][0];
        *(float4*)&w[4] = *(const float4*)&wlds[r][4];
#pragma unroll
        for (int v = 0; v < NV; ++v) {
            acc[v][0] = fmaf(w[v], r4.x, acc[v][0]);
            acc[v][1] = fmaf(w[v], r4.y, acc[v][1]);
            acc[v][2] = fmaf(w[v], r4.z, acc[v][2]);
            acc[v][3] = fmaf(w[v], r4.w, acc[v][3]);
        }
    };

    // 4-deep software pipeline over the valid rows (dynamic bound rr)
    for (int r = 0; r < rr; r += 4) {
        float4 n0 = c0, n1 = c1, n2 = c2, n3 = c3;
        if (r + 4 < rr) {                   // uniform branch
            n0 = src[(r + 4) * 256];
            n1 = src[(r + 5) * 256];
            n2 = src[(r + 6) * 256];
            n3 = src[(r + 7) * 256];
        }
        proc(r + 0, c0); proc(r + 1, c1); proc(r + 2, c2); proc(r + 3, c3);
        c0 = n0; c1 = n1; c2 = n2; c3 = n3;
    }

    // private partial store — no atomics
    float4* np_ = (float4*)pnum;
#pragma unroll
    for (int v = 0; v < NV; ++v)
        np_[(pbase + v) * (ND / 4) + t] =
            make_float4(acc[v][0], acc[v][1], acc[v][2], acc[v][3]);
}

// 512 one-wave blocks: (b, v, quarter-of-d). Each lane owns one float4.
__global__ __launch_bounds__(64) void dvs_reduce(
    const float* __restrict__ pnum,
    const float* __restrict__ pden,
    const int* __restrict__ grid_thws,
    float* __restrict__ out)
{
    const int bv = blockIdx.x >> 2;         // 0..127  (b*NV + v)
    const int q  = blockIdx.x & 3;          // quarter of d
    const int b  = bv >> 3;
    const int v  = bv & (NV - 1);
    const int HW = grid_thws[b * 3 + 1] * grid_thws[b * 3 + 2];
    const int nc = (HW + CHUNK - 1) / CHUNK;
    const int t  = threadIdx.x;             // 0..63
    const int f4 = q * 64 + t;              // float4 index within row, 0..255

    const float4* np_ = (const float4*)pnum;
    const size_t cstride = (size_t)NV * (ND / 4);
    const size_t base = ((size_t)b * NCHUNK * NV + v) * (ND / 4) + f4;
    const int dbase = b * NCHUNK * NV + v;

    float4 s0 = make_float4(0.f, 0.f, 0.f, 0.f), s1 = s0, s2 = s0, s3 = s0;
    float d0 = 0.f, d1 = 0.f, d2 = 0.f, d3 = 0.f;
    int c = 0;
    for (; c + 4 <= nc; c += 4) {           // 4 loads in flight
        float4 p0 = np_[base + (size_t)(c + 0) * cstride];
        float4 p1 = np_[base + (size_t)(c + 1) * cstride];
        float4 p2 = np_[base + (size_t)(c + 2) * cstride];
        float4 p3 = np_[base + (size_t)(c + 3) * cstride];
        d0 += pden[dbase + (c + 0) * NV];
        d1 += pden[dbase + (c + 1) * NV];
        d2 += pden[dbase + (c + 2) * NV];
        d3 += pden[dbase + (c + 3) * NV];
        s0.x += p0.x; s0.y += p0.y; s0.z += p0.z; s0.w += p0.w;
        s1.x += p1.x; s1.y += p1.y; s1.z += p1.z; s1.w += p1.w;
        s2.x += p2.x; s2.y += p2.y; s2.z += p2.z; s2.w += p2.w;
        s3.x += p3.x; s3.y += p3.y; s3.z += p3.z; s3.w += p3.w;
    }
    for (; c < nc; ++c) {
        float4 p0 = np_[base + (size_t)c * cstride];
        d0 += pden[dbase + c * NV];
        s0.x += p0.x; s0.y += p0.y; s0.z += p0.z; s0.w += p0.w;
    }
    const float inv = 1.0f / (d0 + d1 + d2 + d3 + EPS_);
    float4 o = make_float4((s0.x + s1.x + s2.x + s3.x) * inv,
                           (s0.y + s1.y + s2.y + s3.y) * inv,
                           (s0.z + s1.z + s2.z + s3.z) * inv,
                           (s0.w + s1.w + s2.w + s3.w) * inv);
    ((float4*)out)[(size_t)bv * (ND / 4) + f4] = o;
}

extern "C" void kernel_launch(void* const* d_in, const int* in_sizes, int n_in,
                              void* d_out, int out_size, void* d_ws, size_t ws_size,
                              hipStream_t stream) {
    const float* v_pad     = (const float*)d_in[0];
    const float* centers   = (const float*)d_in[1];
    // d_in[2] = v_len (== H*W), unused
    const int*   grid_thws = (const int*)d_in[3];

    float* pnum = (float*)d_ws;
    float* pden = pnum + PNUM_FLOATS;

    dvs_accum<<<NB * NCHUNK, 256, 0, stream>>>(v_pad, centers, grid_thws, pnum, pden);
    dvs_reduce<<<NB * NV * 4, 64, 0, stream>>>(pnum, pden, grid_thws, (float*)d_out);
}